// Round 1
// baseline (1946.036 us; speedup 1.0000x reference)
//
#include <hip/hip_runtime.h>

#define HH 32
#define LOG2E 1.44269504088896340736f

__device__ __forceinline__ float rl(float v, int l) {
    return __int_as_float(__builtin_amdgcn_readlane(__float_as_int(v), l));
}

// 1/(1 + exp2(z * escale))  -- sigmoid when escale = -log2(e)
__device__ __forceinline__ float sigm_e(float z, float escale) {
    return __builtin_amdgcn_rcpf(1.0f + exp2f(z * escale));
}

__global__ __launch_bounds__(64, 1)
void lstm_seq_kernel(const float* __restrict__ input,
                     const float* __restrict__ W_ih1, const float* __restrict__ W_hh1,
                     const float* __restrict__ b_ih1, const float* __restrict__ b_hh1,
                     const float* __restrict__ W_ih2, const float* __restrict__ W_hh2,
                     const float* __restrict__ b_ih2, const float* __restrict__ b_hh2,
                     const float* __restrict__ W_lin, const float* __restrict__ b_lin,
                     float* __restrict__ out, int T, int total)
{
    const int b    = blockIdx.x;    // one wave (64 threads) per batch element
    const int lane = threadIdx.x;
    const int gA   = lane;          // gates 0..63  : i[0..31], f[0..31]
    const int gB   = lane + 64;     // gates 64..127: g[0..31], o[0..31]
    const bool lo  = lane < HH;

    // ---- weights resident in VGPRs: 6 rows x 32 floats per lane ----
    float wh1A[HH], wh1B[HH], wi2A[HH], wi2B[HH], wh2A[HH], wh2B[HH];
    {
        const float4* pA1 = (const float4*)(W_hh1 + gA * HH);
        const float4* pB1 = (const float4*)(W_hh1 + gB * HH);
        const float4* pA2 = (const float4*)(W_ih2 + gA * HH);
        const float4* pB2 = (const float4*)(W_ih2 + gB * HH);
        const float4* pA3 = (const float4*)(W_hh2 + gA * HH);
        const float4* pB3 = (const float4*)(W_hh2 + gB * HH);
#pragma unroll
        for (int q = 0; q < HH / 4; ++q) {
            float4 v;
            v = pA1[q]; wh1A[4*q] = v.x; wh1A[4*q+1] = v.y; wh1A[4*q+2] = v.z; wh1A[4*q+3] = v.w;
            v = pB1[q]; wh1B[4*q] = v.x; wh1B[4*q+1] = v.y; wh1B[4*q+2] = v.z; wh1B[4*q+3] = v.w;
            v = pA2[q]; wi2A[4*q] = v.x; wi2A[4*q+1] = v.y; wi2A[4*q+2] = v.z; wi2A[4*q+3] = v.w;
            v = pB2[q]; wi2B[4*q] = v.x; wi2B[4*q+1] = v.y; wi2B[4*q+2] = v.z; wi2B[4*q+3] = v.w;
            v = pA3[q]; wh2A[4*q] = v.x; wh2A[4*q+1] = v.y; wh2A[4*q+2] = v.z; wh2A[4*q+3] = v.w;
            v = pB3[q]; wh2B[4*q] = v.x; wh2B[4*q+1] = v.y; wh2B[4*q+2] = v.z; wh2B[4*q+3] = v.w;
        }
    }
    const float wxA = W_ih1[gA], wxB = W_ih1[gB];
    const float bA  = b_ih1[gA] + b_hh1[gA];
    const float bB  = b_ih1[gB] + b_hh1[gB];
    const float b2A = b_ih2[gA] + b_hh2[gA];
    const float b2B = b_ih2[gB] + b_hh2[gB];
    const float wlin = lo ? W_lin[lane] : 0.0f;
    const float blin = b_lin[0];

    // gate0 (i or f) is always sigmoid; gate1 is tanh (g, lanes<32) or sigmoid (o)
    const float esB = lo ? (-2.0f * LOG2E) : (-LOG2E);
    const float mB  = lo ? 2.0f : 1.0f;
    const float cBc = lo ? -1.0f : 0.0f;

    float c1 = 0.0f, c2 = 0.0f;
    float h1s[HH], h2s[HH];
#pragma unroll
    for (int k = 0; k < HH; ++k) { h1s[k] = 0.0f; h2s[k] = 0.0f; }

    const float* __restrict__ inp  = input + (size_t)b * T;
    float* __restrict__       outp = out   + (size_t)b * total;
    float xv = 0.0f;  // autoregressive feedback

    for (int t = 0; t < total; ++t) {
        float x;
        if (t < T) x = inp[t];   // wave-uniform -> s_load
        else       x = xv;

        // ---------- LSTM cell 1: z = x*W_ih1 + h1*W_hh1 + b ----------
        float a0 = fmaf(x, wxA, bA), a1 = 0.0f;
        float d0 = fmaf(x, wxB, bB), d1 = 0.0f;
#pragma unroll
        for (int k = 0; k < HH; k += 2) {
            a0 = fmaf(h1s[k],   wh1A[k],   a0);
            a1 = fmaf(h1s[k+1], wh1A[k+1], a1);
            d0 = fmaf(h1s[k],   wh1B[k],   d0);
            d1 = fmaf(h1s[k+1], wh1B[k+1], d1);
        }
        {
            float zA = a0 + a1, zB = d0 + d1;
            float aA = sigm_e(zA, -LOG2E);            // sig(i) | sig(f)
            float aB = fmaf(mB, sigm_e(zB, esB), cBc); // tanh(g) | sig(o)
            float u  = aA * aB;                        // lanes<32: sig(i)*tanh(g)
            float pf = __shfl_xor(aA, 32, 64);         // lanes<32: sig(f)
            float po = __shfl_xor(aB, 32, 64);         // lanes<32: sig(o)
            c1 = fmaf(pf, c1, u);
            float t1 = fmaf(2.0f, sigm_e(c1, -2.0f * LOG2E), -1.0f); // tanh(c1)
            float h1 = po * t1;                        // valid on lanes 0..31
#pragma unroll
            for (int k = 0; k < HH; ++k) h1s[k] = rl(h1, k);
        }

        // ---------- LSTM cell 2: z = h1*W_ih2 + h2*W_hh2 + b ----------
        a0 = b2A; a1 = 0.0f; d0 = b2B; d1 = 0.0f;
#pragma unroll
        for (int k = 0; k < HH; k += 2) {
            a0 = fmaf(h1s[k],   wi2A[k],   a0);
            a1 = fmaf(h1s[k+1], wi2A[k+1], a1);
            d0 = fmaf(h1s[k],   wi2B[k],   d0);
            d1 = fmaf(h1s[k+1], wi2B[k+1], d1);
        }
#pragma unroll
        for (int k = 0; k < HH; k += 2) {
            a0 = fmaf(h2s[k],   wh2A[k],   a0);
            a1 = fmaf(h2s[k+1], wh2A[k+1], a1);
            d0 = fmaf(h2s[k],   wh2B[k],   d0);
            d1 = fmaf(h2s[k+1], wh2B[k+1], d1);
        }
        float h2;
        {
            float zA = a0 + a1, zB = d0 + d1;
            float aA = sigm_e(zA, -LOG2E);
            float aB = fmaf(mB, sigm_e(zB, esB), cBc);
            float u  = aA * aB;
            float pf = __shfl_xor(aA, 32, 64);
            float po = __shfl_xor(aB, 32, 64);
            c2 = fmaf(pf, c2, u);
            float t2 = fmaf(2.0f, sigm_e(c2, -2.0f * LOG2E), -1.0f);
            h2 = po * t2;                              // valid on lanes 0..31
#pragma unroll
            for (int k = 0; k < HH; ++k) h2s[k] = rl(h2, k);
        }

        // ---------- out = h2 @ W_lin^T + b_lin ----------
        float p = h2 * wlin;                           // wlin==0 on lanes>=32
        p += __shfl_xor(p, 16, 64);
        p += __shfl_xor(p,  8, 64);
        p += __shfl_xor(p,  4, 64);
        p += __shfl_xor(p,  2, 64);
        p += __shfl_xor(p,  1, 64);
        float ov = rl(p, 0) + blin;                    // uniform broadcast
        if (lane == 0) outp[t] = ov;
        xv = ov;
    }
}

extern "C" void kernel_launch(void* const* d_in, const int* in_sizes, int n_in,
                              void* d_out, int out_size, void* d_ws, size_t ws_size,
                              hipStream_t stream) {
    const int B = 1024;                 // fixed by the source module
    const int T = in_sizes[0] / B;      // 999
    const int total = out_size / B;     // T + future = 1999

    lstm_seq_kernel<<<dim3(B), dim3(64), 0, stream>>>(
        (const float*)d_in[0],
        (const float*)d_in[1], (const float*)d_in[2],
        (const float*)d_in[3], (const float*)d_in[4],
        (const float*)d_in[5], (const float*)d_in[6],
        (const float*)d_in[7], (const float*)d_in[8],
        (const float*)d_in[9], (const float*)d_in[10],
        (float*)d_out, T, total);
}

// Round 2
// 1757.912 us; speedup vs baseline: 1.1070x; 1.1070x over previous
//
#include <hip/hip_runtime.h>

#define HH 32
#define LOG2E 1.44269504088896340736f

__device__ __forceinline__ float sigm_e(float z, float escale) {
    // 1/(1 + exp2(z*escale)); sigmoid(z) when escale = -log2(e)
    return __builtin_amdgcn_rcpf(1.0f + exp2f(z * escale));
}

__global__ __launch_bounds__(128, 2)
void lstm_seq_kernel(const float* __restrict__ input,
                     const float* __restrict__ W_ih1, const float* __restrict__ W_hh1,
                     const float* __restrict__ b_ih1, const float* __restrict__ b_hh1,
                     const float* __restrict__ W_ih2, const float* __restrict__ W_hh2,
                     const float* __restrict__ b_ih2, const float* __restrict__ b_hh2,
                     const float* __restrict__ W_lin, const float* __restrict__ b_lin,
                     float* __restrict__ out, int T, int total)
{
    const int b    = blockIdx.x;        // one block (2 waves) per batch element
    const int tid  = threadIdx.x;       // 0..127
    const int w    = tid >> 6;          // wave id 0/1
    const int lane = tid & 63;
    const int q    = lane >> 4;         // gate type: 0=i 1=f 2=g 3=o
    const int m    = lane & 15;
    const int j    = (w << 4) | m;      // channel 0..31 (wave0: 0..15, wave1: 16..31)
    const int row  = (q << 5) | j;      // gate row 0..127

    __shared__ __align__(16) float h1buf[HH];
    __shared__ __align__(16) float h2buf[HH];

    // ---- resident weights: 4 rows x 32 = 128 floats/lane (fits arch VGPRs @ 2 waves/EU) ----
    float wh1[HH], wi2[HH], wh2[HH], wlin[HH];
    {
        const float4* p1 = (const float4*)(W_hh1 + row * HH);
        const float4* p2 = (const float4*)(W_ih2 + row * HH);
        const float4* p3 = (const float4*)(W_hh2 + row * HH);
        const float4* p4 = (const float4*)(W_lin);   // same for all lanes (replicated)
#pragma unroll
        for (int r = 0; r < HH / 4; ++r) {
            float4 v;
            v = p1[r]; wh1[4*r] = v.x; wh1[4*r+1] = v.y; wh1[4*r+2] = v.z; wh1[4*r+3] = v.w;
            v = p2[r]; wi2[4*r] = v.x; wi2[4*r+1] = v.y; wi2[4*r+2] = v.z; wi2[4*r+3] = v.w;
            v = p3[r]; wh2[4*r] = v.x; wh2[4*r+1] = v.y; wh2[4*r+2] = v.z; wh2[4*r+3] = v.w;
            v = p4[r]; wlin[4*r] = v.x; wlin[4*r+1] = v.y; wlin[4*r+2] = v.z; wlin[4*r+3] = v.w;
        }
    }
    const float wx   = W_ih1[row];
    const float b1   = b_ih1[row] + b_hh1[row];
    const float b2   = b_ih2[row] + b_hh2[row];
    const float blin = b_lin[0];

    // gate g (q==2) uses tanh = 2*sigmoid(2z)-1; i/f/o use sigmoid
    const bool  isg = (q == 2);
    const float es  = isg ? (-2.0f * LOG2E) : (-LOG2E);
    const float mm  = isg ? 2.0f : 1.0f;
    const float cc  = isg ? -1.0f : 0.0f;

    float c1 = 0.0f, c2 = 0.0f;           // channel state, valid on lanes<16
    float h1bc[HH], h2bc[HH];             // wave-uniform broadcast of h1/h2
#pragma unroll
    for (int k = 0; k < HH; ++k) { h1bc[k] = 0.0f; h2bc[k] = 0.0f; }

    const float* __restrict__ inp  = input + (size_t)b * T;
    float* __restrict__       outp = out   + (size_t)b * total;
    float xcur = inp[0];

    for (int t = 0; t < total; ++t) {
        // prefetch next teacher-forced input (uniform -> s_load), hidden under compute
        int tn = t + 1; if (tn >= T) tn = T - 1;
        float xnext = inp[tn];

        // ---------- cell 1: z1 = x*W_ih1 + h1*W_hh1 + b ----------
        float a0 = fmaf(xcur, wx, b1), a1 = 0.0f, a2 = 0.0f, a3 = 0.0f;
#pragma unroll
        for (int k = 0; k < HH; k += 4) {
            a0 = fmaf(h1bc[k],   wh1[k],   a0);
            a1 = fmaf(h1bc[k+1], wh1[k+1], a1);
            a2 = fmaf(h1bc[k+2], wh1[k+2], a2);
            a3 = fmaf(h1bc[k+3], wh1[k+3], a3);
        }
        {
            float z1  = (a0 + a1) + (a2 + a3);
            float act = fmaf(mm, sigm_e(z1, es), cc);       // sig(i/f/o) | tanh(g)
            float sf  = __shfl_xor(act, 16, 64);            // lanes<16: sig(f)
            float tg  = __shfl_xor(act, 32, 64);            // lanes<16: tanh(g)
            float so  = __shfl_xor(act, 48, 64);            // lanes<16: sig(o)
            c1 = fmaf(sf, c1, act * tg);
            float th = fmaf(2.0f, sigm_e(c1, -2.0f * LOG2E), -1.0f);  // tanh(c1)
            float h1 = so * th;                              // valid on lanes<16
            if (lane < 16) h1buf[j] = h1;
        }

        // ---------- cell 2 partial: b2 + h2_prev*W_hh2 (fills barrier-1 shadow) ----------
        float e0 = b2, e1 = 0.0f, e2 = 0.0f, e3 = 0.0f;
#pragma unroll
        for (int k = 0; k < HH; k += 4) {
            e0 = fmaf(h2bc[k],   wh2[k],   e0);
            e1 = fmaf(h2bc[k+1], wh2[k+1], e1);
            e2 = fmaf(h2bc[k+2], wh2[k+2], e2);
            e3 = fmaf(h2bc[k+3], wh2[k+3], e3);
        }

        __syncthreads();                                     // barrier 1: h1 visible
#pragma unroll
        for (int r = 0; r < HH / 4; ++r) {                   // broadcast read (conflict-free)
            float4 v = ((const float4*)h1buf)[r];
            h1bc[4*r] = v.x; h1bc[4*r+1] = v.y; h1bc[4*r+2] = v.z; h1bc[4*r+3] = v.w;
        }

        // ---------- cell 2 rest: + h1*W_ih2 ----------
#pragma unroll
        for (int k = 0; k < HH; k += 4) {
            e0 = fmaf(h1bc[k],   wi2[k],   e0);
            e1 = fmaf(h1bc[k+1], wi2[k+1], e1);
            e2 = fmaf(h1bc[k+2], wi2[k+2], e2);
            e3 = fmaf(h1bc[k+3], wi2[k+3], e3);
        }
        {
            float z2   = (e0 + e1) + (e2 + e3);
            float act2 = fmaf(mm, sigm_e(z2, es), cc);
            float sf   = __shfl_xor(act2, 16, 64);
            float tg   = __shfl_xor(act2, 32, 64);
            float so   = __shfl_xor(act2, 48, 64);
            c2 = fmaf(sf, c2, act2 * tg);
            float th = fmaf(2.0f, sigm_e(c2, -2.0f * LOG2E), -1.0f);  // tanh(c2)
            float h2 = so * th;
            if (lane < 16) h2buf[j] = h2;
        }

        __syncthreads();                                     // barrier 2: h2 visible
#pragma unroll
        for (int r = 0; r < HH / 4; ++r) {
            float4 v = ((const float4*)h2buf)[r];
            h2bc[4*r] = v.x; h2bc[4*r+1] = v.y; h2bc[4*r+2] = v.z; h2bc[4*r+3] = v.w;
        }

        // ---------- out = h2 @ W_lin^T + b_lin (redundant per-lane; no broadcast needed) ----
        float o0 = blin, o1 = 0.0f, o2 = 0.0f, o3 = 0.0f;
#pragma unroll
        for (int k = 0; k < HH; k += 4) {
            o0 = fmaf(h2bc[k],   wlin[k],   o0);
            o1 = fmaf(h2bc[k+1], wlin[k+1], o1);
            o2 = fmaf(h2bc[k+2], wlin[k+2], o2);
            o3 = fmaf(h2bc[k+3], wlin[k+3], o3);
        }
        float ov = (o0 + o1) + (o2 + o3);
        if (tid == 0) outp[t] = ov;

        xcur = (t + 1 < T) ? xnext : ov;                     // autoregressive feedback
    }
}

extern "C" void kernel_launch(void* const* d_in, const int* in_sizes, int n_in,
                              void* d_out, int out_size, void* d_ws, size_t ws_size,
                              hipStream_t stream) {
    const int B = 1024;                 // fixed by the source module
    const int T = in_sizes[0] / B;      // 999
    const int total = out_size / B;     // T + future = 1999

    lstm_seq_kernel<<<dim3(B), dim3(128), 0, stream>>>(
        (const float*)d_in[0],
        (const float*)d_in[1], (const float*)d_in[2],
        (const float*)d_in[3], (const float*)d_in[4],
        (const float*)d_in[5], (const float*)d_in[6],
        (const float*)d_in[7], (const float*)d_in[8],
        (const float*)d_in[9], (const float*)d_in[10],
        (float*)d_out, T, total);
}

// Round 3
// 1737.213 us; speedup vs baseline: 1.1202x; 1.0119x over previous
//
#include <hip/hip_runtime.h>

#define HH 32
#define LOG2E 1.44269504088896340736f

#if defined(__has_builtin)
#if __has_builtin(__builtin_amdgcn_exp2f)
#define EXP2F(x) __builtin_amdgcn_exp2f(x)
#else
#define EXP2F(x) exp2f(x)
#endif
#else
#define EXP2F(x) exp2f(x)
#endif

// ds_swizzle BitMode: offset = xor_mask<<10 | or_mask<<5 | and_mask(0x1F)
#define SWZ(v, pat) __int_as_float(__builtin_amdgcn_ds_swizzle(__float_as_int(v), (pat)))

__device__ __forceinline__ float sigm_e(float z, float escale) {
    // 1/(1 + exp2(z*escale)); sigmoid(z) when escale = -log2(e)
    return __builtin_amdgcn_rcpf(1.0f + EXP2F(z * escale));
}

__global__ __launch_bounds__(128, 2)
void lstm_seq_kernel(const float* __restrict__ input,
                     const float* __restrict__ W_ih1, const float* __restrict__ W_hh1,
                     const float* __restrict__ b_ih1, const float* __restrict__ b_hh1,
                     const float* __restrict__ W_ih2, const float* __restrict__ W_hh2,
                     const float* __restrict__ b_ih2, const float* __restrict__ b_hh2,
                     const float* __restrict__ W_lin, const float* __restrict__ b_lin,
                     float* __restrict__ out, int T, int total)
{
    const int b    = blockIdx.x;     // one block (2 waves) per batch element
    const int tid  = threadIdx.x;    // 0..127
    const int w    = tid >> 6;       // wave 0/1
    const int lane = tid & 63;
    const int q    = lane & 3;       // gate: 0=i 1=f 2=g 3=o  (xor-1/2/3 neighbors)
    const int m    = lane >> 2;      // channel-within-wave 0..15
    const int j    = (w << 4) | m;   // channel 0..31
    const int row  = (q << 5) | j;   // gate row 0..127 (PyTorch i,f,g,o blocks)

    __shared__ __align__(16) float h1buf[HH];
    __shared__ __align__(16) float h2buf[HH];

    // ---- resident weights: 3 rows x 32 = 96 floats/lane (the ONLY big arrays) ----
    float4 wh1v[8], wi2v[8], wh2v[8];
    {
        const float4* p1 = (const float4*)(W_hh1 + row * HH);
        const float4* p2 = (const float4*)(W_ih2 + row * HH);
        const float4* p3 = (const float4*)(W_hh2 + row * HH);
#pragma unroll
        for (int r = 0; r < 8; ++r) { wh1v[r] = p1[r]; wi2v[r] = p2[r]; wh2v[r] = p3[r]; }
    }
    const float wx   = W_ih1[row];
    const float b1   = b_ih1[row] + b_hh1[row];
    const float b2   = b_ih2[row] + b_hh2[row];
    const float wlin = W_lin[lane & 31];   // one scalar per lane (channel lane&31)
    const float blin = b_lin[0];

    // gate g (q==2) uses tanh = 2*sigmoid(2z)-1; i/f/o use sigmoid
    const bool  isg = (q == 2);
    const float es  = isg ? (-2.0f * LOG2E) : (-LOG2E);
    const float mm  = isg ? 2.0f : 1.0f;
    const float cc  = isg ? -1.0f : 0.0f;

    float c1 = 0.0f, c2 = 0.0f;      // valid on q==0 lanes (others harmless garbage)
    float ov = 0.0f;                 // previous output, all lanes (feedback)
    float4 h1v[8], h2v[8];           // broadcast h1/h2 in registers
#pragma unroll
    for (int r = 0; r < 8; ++r) {
        h1v[r] = make_float4(0.f, 0.f, 0.f, 0.f);
        h2v[r] = make_float4(0.f, 0.f, 0.f, 0.f);
    }

    const float* __restrict__ inp  = input + (size_t)b * T;
    float* __restrict__       outp = out   + (size_t)b * total;

    for (int t = 0; t < total; ++t) {
        float xin = inp[t < T ? t : (T - 1)];        // uniform load, hidden by FMAs
        float x   = (t < T) ? xin : ov;              // autoregressive feedback in-reg

        // ---------- P0: z1 = x*wx + h1*W_hh1 + b1  AND  e = h2*W_hh2 + b2 ----------
        float a0 = fmaf(x, wx, b1), a1 = 0.f, a2 = 0.f, a3 = 0.f;
        float e0 = b2,              e1 = 0.f, e2 = 0.f, e3 = 0.f;
#pragma unroll
        for (int r = 0; r < 8; ++r) {
            a0 = fmaf(h1v[r].x, wh1v[r].x, a0);
            a1 = fmaf(h1v[r].y, wh1v[r].y, a1);
            a2 = fmaf(h1v[r].z, wh1v[r].z, a2);
            a3 = fmaf(h1v[r].w, wh1v[r].w, a3);
            e0 = fmaf(h2v[r].x, wh2v[r].x, e0);
            e1 = fmaf(h2v[r].y, wh2v[r].y, e1);
            e2 = fmaf(h2v[r].z, wh2v[r].z, e2);
            e3 = fmaf(h2v[r].w, wh2v[r].w, e3);
        }
        {
            float z1  = (a0 + a1) + (a2 + a3);
            float act = fmaf(mm, sigm_e(z1, es), cc);   // sig(i/f/o) | tanh(g)
            float vf  = SWZ(act, 0x041F);               // q=0 lane: gate f
            float vg  = SWZ(act, 0x081F);               // q=0 lane: gate g
            float vo  = SWZ(act, 0x0C1F);               // q=0 lane: gate o
            c1 = fmaf(vf, c1, act * vg);
            float th = fmaf(2.0f, sigm_e(c1, -2.0f * LOG2E), -1.0f);  // tanh(c1)
            float h1 = vo * th;                          // valid on q==0 lanes
            if (q == 0) h1buf[j] = h1;
        }

        __syncthreads();                                 // B1: h1 visible

        // ---------- P1: e += h1*W_ih2 ; cell-2 nonlinearity ----------
#pragma unroll
        for (int r = 0; r < 8; ++r) {
            float4 hv = ((const float4*)h1buf)[r];       // broadcast read
            h1v[r] = hv;                                  // keep for next step's z1
            e0 = fmaf(hv.x, wi2v[r].x, e0);
            e1 = fmaf(hv.y, wi2v[r].y, e1);
            e2 = fmaf(hv.z, wi2v[r].z, e2);
            e3 = fmaf(hv.w, wi2v[r].w, e3);
        }
        {
            float z2   = (e0 + e1) + (e2 + e3);
            float act2 = fmaf(mm, sigm_e(z2, es), cc);
            float vf   = SWZ(act2, 0x041F);
            float vg   = SWZ(act2, 0x081F);
            float vo   = SWZ(act2, 0x0C1F);
            c2 = fmaf(vf, c2, act2 * vg);
            float th = fmaf(2.0f, sigm_e(c2, -2.0f * LOG2E), -1.0f);  // tanh(c2)
            float h2 = vo * th;                           // valid on q==0 lanes
            if (q == 0) h2buf[j] = h2;
        }

        __syncthreads();                                 // B2: h2 visible

        // ---------- P2: reload h2 broadcast; out = h2 @ W_lin^T + b_lin ----------
#pragma unroll
        for (int r = 0; r < 8; ++r) h2v[r] = ((const float4*)h2buf)[r];

        float p = h2buf[lane & 31] * wlin;               // distributed product
        p += SWZ(p, 0x041F);                             // butterfly sum over 32 ch
        p += SWZ(p, 0x081F);
        p += SWZ(p, 0x101F);
        p += SWZ(p, 0x201F);
        p += SWZ(p, 0x401F);
        ov = p + blin;                                   // all lanes hold out(t)
        if (tid == 0) outp[t] = ov;
    }
}

extern "C" void kernel_launch(void* const* d_in, const int* in_sizes, int n_in,
                              void* d_out, int out_size, void* d_ws, size_t ws_size,
                              hipStream_t stream) {
    const int B = 1024;                 // fixed by the source module
    const int T = in_sizes[0] / B;      // 999
    const int total = out_size / B;     // T + future = 1999

    lstm_seq_kernel<<<dim3(B), dim3(128), 0, stream>>>(
        (const float*)d_in[0],
        (const float*)d_in[1], (const float*)d_in[2],
        (const float*)d_in[3], (const float*)d_in[4],
        (const float*)d_in[5], (const float*)d_in[6],
        (const float*)d_in[7], (const float*)d_in[8],
        (const float*)d_in[9], (const float*)d_in[10],
        (float*)d_out, T, total);
}

// Round 4
// 1523.613 us; speedup vs baseline: 1.2773x; 1.1402x over previous
//
#include <hip/hip_runtime.h>

#define HH 32
#define LOG2E 1.44269504088896340736f

// DPP quad_perm controls: xor within the 4-lane gate group (q = lane&3)
#define QP_XOR1 0xB1   // [1,0,3,2]
#define QP_XOR2 0x4E   // [2,3,0,1]
#define QP_XOR3 0x1B   // [3,2,1,0]
#define QPERM(v, ctrl) \
    __int_as_float(__builtin_amdgcn_update_dpp(0, __float_as_int(v), (ctrl), 0xF, 0xF, true))

__device__ __forceinline__ float hw_exp2(float x) {
    float r;
    asm("v_exp_f32 %0, %1" : "=v"(r) : "v"(x));   // guaranteed HW exp2, 1 instr
    return r;
}
__device__ __forceinline__ float sigm_e(float z, float escale) {
    // 1/(1 + exp2(z*escale)); sigmoid(z) when escale = -log2(e)
    return __builtin_amdgcn_rcpf(1.0f + hw_exp2(z * escale));
}

__global__ __launch_bounds__(128, 2)
void lstm_seq_kernel(const float* __restrict__ input,
                     const float* __restrict__ W_ih1, const float* __restrict__ W_hh1,
                     const float* __restrict__ b_ih1, const float* __restrict__ b_hh1,
                     const float* __restrict__ W_ih2, const float* __restrict__ W_hh2,
                     const float* __restrict__ b_ih2, const float* __restrict__ b_hh2,
                     const float* __restrict__ W_lin, const float* __restrict__ b_lin,
                     float* __restrict__ out, int T, int total)
{
    const int b    = blockIdx.x;     // one block (2 waves) per batch element
    const int tid  = threadIdx.x;    // 0..127
    const int w    = tid >> 6;       // wave 0/1
    const int lane = tid & 63;
    const int q    = lane & 3;       // gate: 0=i 1=f 2=g 3=o (quad_perm neighbors)
    const int m    = lane >> 2;      // channel-within-wave 0..15
    const int j    = (w << 4) | m;   // channel 0..31
    const int row  = (q << 5) | j;   // gate row 0..127 (PyTorch i,f,g,o blocks)

    __shared__ __align__(16) float h1buf[HH];
    __shared__ __align__(16) float h2buf[HH];

    // ---- resident weights: 4 arrays x 32 = 128 floats/lane ----
    float4 wh1v[8], wi2v[8], wh2v[8], wlv[8];
    {
        const float4* p1 = (const float4*)(W_hh1 + row * HH);
        const float4* p2 = (const float4*)(W_ih2 + row * HH);
        const float4* p3 = (const float4*)(W_hh2 + row * HH);
        const float4* p4 = (const float4*)(W_lin);        // replicated on all lanes
#pragma unroll
        for (int r = 0; r < 8; ++r) {
            wh1v[r] = p1[r]; wi2v[r] = p2[r]; wh2v[r] = p3[r]; wlv[r] = p4[r];
        }
    }
    const float wx   = W_ih1[row];
    const float b1   = b_ih1[row] + b_hh1[row];
    const float b2   = b_ih2[row] + b_hh2[row];
    const float blin = b_lin[0];

    // gate g (q==2) uses tanh = 2*sigmoid(2z)-1; i/f/o use sigmoid
    const bool  isg = (q == 2);
    const float es  = isg ? (-2.0f * LOG2E) : (-LOG2E);
    const float mm  = isg ? 2.0f : 1.0f;
    const float cc  = isg ? -1.0f : 0.0f;

    float c1 = 0.0f, c2 = 0.0f;      // valid on q==0 lanes (others harmless garbage)
    float ov = 0.0f;                 // previous output (all lanes, feedback)
    // carried partials: a = b1 + Wh1*h1(t-1), e = b2 + Wh2*h2(t-1)
    float a0 = b1, a1 = 0.f, a2 = 0.f, a3 = 0.f;
    float e0 = b2, e1 = 0.f, e2 = 0.f, e3 = 0.f;

    const float* __restrict__ inp  = input + (size_t)b * T;
    float* __restrict__       outp = out   + (size_t)b * total;

    for (int t = 0; t < total; ++t) {
        float xin = inp[t < T ? t : (T - 1)];    // uniform load
        float x   = (t < T) ? xin : ov;          // autoregressive feedback in-reg

        // ---------- P0: z1 from carried partial (short critical path) ----------
        float z1  = fmaf(x, wx, (a0 + a1) + (a2 + a3));
        float act = fmaf(mm, sigm_e(z1, es), cc);       // sig(i/f/o) | tanh(g)
        float vf  = QPERM(act, QP_XOR1);                // q=0 lane: gate f
        float vg  = QPERM(act, QP_XOR2);                // q=0 lane: gate g
        float vo  = QPERM(act, QP_XOR3);                // q=0 lane: gate o
        c1 = fmaf(vf, c1, act * vg);
        float h1 = vo * fmaf(2.0f, sigm_e(c1, -2.0f * LOG2E), -1.0f);  // tanh(c1)
        if (q == 0) h1buf[j] = h1;

        __syncthreads();                                 // B1: h1 visible

        // ---------- P1: one h1 read feeds BOTH z2 and next-step's z1 partial ----
        float4 hv[8];
#pragma unroll
        for (int r = 0; r < 8; ++r) hv[r] = ((const float4*)h1buf)[r];
        a0 = b1; a1 = 0.f; a2 = 0.f; a3 = 0.f;
#pragma unroll
        for (int r = 0; r < 8; ++r) {
            e0 = fmaf(hv[r].x, wi2v[r].x, e0);
            e1 = fmaf(hv[r].y, wi2v[r].y, e1);
            e2 = fmaf(hv[r].z, wi2v[r].z, e2);
            e3 = fmaf(hv[r].w, wi2v[r].w, e3);
            a0 = fmaf(hv[r].x, wh1v[r].x, a0);
            a1 = fmaf(hv[r].y, wh1v[r].y, a1);
            a2 = fmaf(hv[r].z, wh1v[r].z, a2);
            a3 = fmaf(hv[r].w, wh1v[r].w, a3);
        }
        {
            float z2   = (e0 + e1) + (e2 + e3);
            float act2 = fmaf(mm, sigm_e(z2, es), cc);
            float vf2  = QPERM(act2, QP_XOR1);
            float vg2  = QPERM(act2, QP_XOR2);
            float vo2  = QPERM(act2, QP_XOR3);
            c2 = fmaf(vf2, c2, act2 * vg2);
            float h2 = vo2 * fmaf(2.0f, sigm_e(c2, -2.0f * LOG2E), -1.0f); // tanh(c2)
            if (q == 0) h2buf[j] = h2;
        }

        __syncthreads();                                 // B2: h2 visible

        // ---------- P2: one h2 read feeds BOTH next z2 partial and the output ----
        float4 gv[8];
#pragma unroll
        for (int r = 0; r < 8; ++r) gv[r] = ((const float4*)h2buf)[r];
        e0 = b2; e1 = 0.f; e2 = 0.f; e3 = 0.f;
        float o0 = blin, o1 = 0.f, o2 = 0.f, o3 = 0.f;
#pragma unroll
        for (int r = 0; r < 8; ++r) {
            e0 = fmaf(gv[r].x, wh2v[r].x, e0);
            e1 = fmaf(gv[r].y, wh2v[r].y, e1);
            e2 = fmaf(gv[r].z, wh2v[r].z, e2);
            e3 = fmaf(gv[r].w, wh2v[r].w, e3);
            o0 = fmaf(gv[r].x, wlv[r].x, o0);
            o1 = fmaf(gv[r].y, wlv[r].y, o1);
            o2 = fmaf(gv[r].z, wlv[r].z, o2);
            o3 = fmaf(gv[r].w, wlv[r].w, o3);
        }
        ov = (o0 + o1) + (o2 + o3);                      // all lanes, redundantly
        if (tid == 0) outp[t] = ov;
    }
}

extern "C" void kernel_launch(void* const* d_in, const int* in_sizes, int n_in,
                              void* d_out, int out_size, void* d_ws, size_t ws_size,
                              hipStream_t stream) {
    const int B = 1024;                 // fixed by the source module
    const int T = in_sizes[0] / B;      // 999
    const int total = out_size / B;     // T + future = 1999

    lstm_seq_kernel<<<dim3(B), dim3(128), 0, stream>>>(
        (const float*)d_in[0],
        (const float*)d_in[1], (const float*)d_in[2],
        (const float*)d_in[3], (const float*)d_in[4],
        (const float*)d_in[5], (const float*)d_in[6],
        (const float*)d_in[7], (const float*)d_in[8],
        (const float*)d_in[9], (const float*)d_in[10],
        (float*)d_out, T, total);
}